// Round 13
// baseline (232.540 us; speedup 1.0000x reference)
//
#include <hip/hip_runtime.h>
#include <math.h>

#define NN 100000
#define EE 1600000
#define KB 256          // buckets
#define RR 391          // ceil(NN / KB); srel < 391, dst < 2^17
#define CAP 8192        // per-bucket capacity (avg 6250, sigma ~76)
#define NPART 782       // part blocks: 2048 edges each
#define NPROJ 782       // proj blocks: 128 nodes each

// ================= D0: P = W0 @ W1 @ [rowsum(w_rate0) | w_rate1 | w_alpha]; also zero gcur =================
// 1024 threads; 8 lanes/row (16 consecutive floats each) -> coalesced.  (R5-verified body.)

__global__ __launch_bounds__(1024) void k_pmat(const float* __restrict__ w_gcn0,
                                               const float* __restrict__ w_gcn1,
                                               const float* __restrict__ w_rate0,
                                               const float* __restrict__ w_rate1,
                                               const float* __restrict__ w_alpha,
                                               float* __restrict__ Pt0, float* __restrict__ Pt1,
                                               float* __restrict__ Pt2, int* __restrict__ gcur) {
    __shared__ float V0[128], V1[128], V2[128];
    __shared__ float Q0[128], Q1[128], Q2[128];
    int t = threadIdx.x;
    if (t < KB) gcur[t] = 0;
    int r = t >> 3, seg = t & 7;
    {   // V0 = rowsum(w_rate0)
        const float* p = w_rate0 + r * 128 + seg * 16;
        float s = 0.f;
        #pragma unroll
        for (int k = 0; k < 16; ++k) s += p[k];
        s += __shfl_down(s, 4, 8); s += __shfl_down(s, 2, 8); s += __shfl_down(s, 1, 8);
        if (seg == 0) V0[r] = s;
    }
    if (t < 128) { V1[t] = w_rate1[t]; V2[t] = w_alpha[t]; }
    __syncthreads();
    {   // Q = w_gcn1 @ V
        const float* p = w_gcn1 + r * 128 + seg * 16;
        float q0 = 0.f, q1 = 0.f, q2 = 0.f;
        #pragma unroll
        for (int k = 0; k < 16; ++k) {
            float w = p[k]; int j = seg * 16 + k;
            q0 += w * V0[j]; q1 += w * V1[j]; q2 += w * V2[j];
        }
        q0 += __shfl_down(q0, 4, 8); q0 += __shfl_down(q0, 2, 8); q0 += __shfl_down(q0, 1, 8);
        q1 += __shfl_down(q1, 4, 8); q1 += __shfl_down(q1, 2, 8); q1 += __shfl_down(q1, 1, 8);
        q2 += __shfl_down(q2, 4, 8); q2 += __shfl_down(q2, 2, 8); q2 += __shfl_down(q2, 1, 8);
        if (seg == 0) { Q0[r] = q0; Q1[r] = q1; Q2[r] = q2; }
    }
    __syncthreads();
    {   // P = w_gcn0 @ Q
        const float* p = w_gcn0 + r * 128 + seg * 16;
        float q0 = 0.f, q1 = 0.f, q2 = 0.f;
        #pragma unroll
        for (int k = 0; k < 16; ++k) {
            float w = p[k]; int j = seg * 16 + k;
            q0 += w * Q0[j]; q1 += w * Q1[j]; q2 += w * Q2[j];
        }
        q0 += __shfl_down(q0, 4, 8); q0 += __shfl_down(q0, 2, 8); q0 += __shfl_down(q0, 1, 8);
        q1 += __shfl_down(q1, 4, 8); q1 += __shfl_down(q1, 2, 8); q1 += __shfl_down(q1, 1, 8);
        q2 += __shfl_down(q2, 4, 8); q2 += __shfl_down(q2, 2, 8); q2 += __shfl_down(q2, 1, 8);
        if (seg == 0) { Pt0[r] = q0; Pt1[r] = q1; Pt2[r] = q2; }
    }
}

// ================= D1: part (even blocks) ∥ proj (odd blocks), 1564 x 512 =================
// part: 2048 edges/block (4/thread, int4), single-pass rank capture.
// proj: 128 nodes/block, unroll-4 (4 h float4 loads in flight per half-wave).

__global__ __launch_bounds__(512) void k_part_proj(const int* __restrict__ src, const int* __restrict__ dst,
                                                   int* __restrict__ gcur, unsigned int* __restrict__ pk,
                                                   const float* __restrict__ h,
                                                   const float* __restrict__ Pt0, const float* __restrict__ Pt1,
                                                   const float* __restrict__ Pt2,
                                                   float4* __restrict__ u4) {
    __shared__ int cnt[KB];
    __shared__ int base[KB];
    __shared__ alignas(16) float sP0[128], sP1[128], sP2[128];
    int t = threadIdx.x;
    int role = blockIdx.x & 1;
    int id = blockIdx.x >> 1;

    if (role == 0) {
        // ---------------- partition: pk = dst | srel<<17 ----------------
        if (t < KB) cnt[t] = 0;
        __syncthreads();
        int e0 = id * 2048 + t * 4;
        unsigned int pkv[4];
        int bkt[4], rnk[4];
        if (e0 + 4 <= EE) {
            int4 sa = *(const int4*)(src + e0);
            int4 da = *(const int4*)(dst + e0);
            int ss[4] = { sa.x, sa.y, sa.z, sa.w };
            int dd[4] = { da.x, da.y, da.z, da.w };
            #pragma unroll
            for (int i = 0; i < 4; ++i) {
                int b = ss[i] / RR;
                bkt[i] = b;
                pkv[i] = (unsigned int)dd[i] | ((unsigned int)(ss[i] - b * RR) << 17);
                rnk[i] = atomicAdd(&cnt[b], 1);        // rank within block, single pass
            }
        } else {
            #pragma unroll
            for (int i = 0; i < 4; ++i) {
                int e = e0 + i;
                if (e < EE) {
                    int s = src[e], d = dst[e];
                    int b = s / RR;
                    bkt[i] = b;
                    pkv[i] = (unsigned int)d | ((unsigned int)(s - b * RR) << 17);
                    rnk[i] = atomicAdd(&cnt[b], 1);
                } else bkt[i] = -1;
            }
        }
        __syncthreads();
        if (t < KB) base[t] = cnt[t] ? atomicAdd(&gcur[t], cnt[t]) : 0;   // gcur zeroed by k_pmat
        __syncthreads();
        #pragma unroll
        for (int i = 0; i < 4; ++i) {
            if (bkt[i] >= 0) {
                int rel = base[bkt[i]] + rnk[i];
                if (rel < CAP) pk[bkt[i] * CAP + rel] = pkv[i];   // overflow guard (stat. impossible)
            }
        }
    } else {
        // ---------------- raw projection u = h @ P, unroll-4 ----------------
        if (t < 128) { sP0[t] = Pt0[t]; sP1[t] = Pt1[t]; sP2[t] = Pt2[t]; }
        __syncthreads();
        int hw = t >> 5;       // 0..15
        int l32 = t & 31;
        int c4 = l32 * 4;
        float4 c0 = *(const float4*)(sP0 + c4);
        float4 c1 = *(const float4*)(sP1 + c4);
        float4 c2 = *(const float4*)(sP2 + c4);
        int nlo = id * 128;
        #pragma unroll
        for (int half = 0; half < 2; ++half) {
            int na = nlo + half * 64 + hw;        // 4 nodes, stride 16
            int nb = na + 16;
            int nc = na + 32;
            int nd = na + 48;
            bool vA = na < NN, vB = nb < NN, vC = nc < NN, vD = nd < NN;
            float4 z = make_float4(0.f, 0.f, 0.f, 0.f);
            float4 ha = vA ? *(const float4*)(h + (size_t)na * 128 + c4) : z;
            float4 hb = vB ? *(const float4*)(h + (size_t)nb * 128 + c4) : z;
            float4 hc = vC ? *(const float4*)(h + (size_t)nc * 128 + c4) : z;
            float4 hd = vD ? *(const float4*)(h + (size_t)nd * 128 + c4) : z;
            float a0 = ha.x*c0.x + ha.y*c0.y + ha.z*c0.z + ha.w*c0.w;
            float a1 = ha.x*c1.x + ha.y*c1.y + ha.z*c1.z + ha.w*c1.w;
            float a2 = ha.x*c2.x + ha.y*c2.y + ha.z*c2.z + ha.w*c2.w;
            float b0 = hb.x*c0.x + hb.y*c0.y + hb.z*c0.z + hb.w*c0.w;
            float b1 = hb.x*c1.x + hb.y*c1.y + hb.z*c1.z + hb.w*c1.w;
            float b2 = hb.x*c2.x + hb.y*c2.y + hb.z*c2.z + hb.w*c2.w;
            float g0 = hc.x*c0.x + hc.y*c0.y + hc.z*c0.z + hc.w*c0.w;
            float g1 = hc.x*c1.x + hc.y*c1.y + hc.z*c1.z + hc.w*c1.w;
            float g2 = hc.x*c2.x + hc.y*c2.y + hc.z*c2.z + hc.w*c2.w;
            float d0 = hd.x*c0.x + hd.y*c0.y + hd.z*c0.z + hd.w*c0.w;
            float d1 = hd.x*c1.x + hd.y*c1.y + hd.z*c1.z + hd.w*c1.w;
            float d2 = hd.x*c2.x + hd.y*c2.y + hd.z*c2.z + hd.w*c2.w;
            #pragma unroll
            for (int off = 16; off > 0; off >>= 1) {
                a0 += __shfl_down(a0, off, 32); a1 += __shfl_down(a1, off, 32); a2 += __shfl_down(a2, off, 32);
                b0 += __shfl_down(b0, off, 32); b1 += __shfl_down(b1, off, 32); b2 += __shfl_down(b2, off, 32);
                g0 += __shfl_down(g0, off, 32); g1 += __shfl_down(g1, off, 32); g2 += __shfl_down(g2, off, 32);
                d0 += __shfl_down(d0, off, 32); d1 += __shfl_down(d1, off, 32); d2 += __shfl_down(d2, off, 32);
            }
            if (l32 == 0) {
                if (vA) { float* up = (float*)&u4[na]; *(float2*)up = make_float2(a0, a1); up[2] = a2; }
                if (vB) { float* up = (float*)&u4[nb]; *(float2*)up = make_float2(b0, b1); up[2] = b2; }
                if (vC) { float* up = (float*)&u4[nc]; *(float2*)up = make_float2(g0, g1); up[2] = g2; }
                if (vD) { float* up = (float*)&u4[nd]; *(float2*)up = make_float2(d0, d1); up[2] = d2; }
            }
        }
    }
}

// ================= D2: cnt: degrees from pk -> nrm[]; stow nrm into u4.w =================

__global__ __launch_bounds__(1024) void k_cnt(const unsigned int* __restrict__ pk,
                                              const int* __restrict__ gcur,
                                              float* __restrict__ nrm, float4* __restrict__ u4) {
    __shared__ int c[RR];
    int b = blockIdx.x;
    int t = threadIdx.x;
    int nlo = b * RR;
    int nn = NN - nlo; if (nn > RR) nn = RR;
    if (nn <= 0) return;
    if (t < RR) c[t] = 0;
    __syncthreads();
    const unsigned int* P = pk + b * CAP;
    int m = gcur[b]; if (m > CAP) m = CAP;
    for (int i = t; i < m; i += 1024) atomicAdd(&c[P[i] >> 17], 1);
    __syncthreads();
    if (t < nn) {
        float nv = rsqrtf((float)c[t]);
        nrm[nlo + t] = nv;
        ((float*)&u4[nlo + t])[3] = nv;    // .w only
    }
}

// ================= D3/D4: bucketed aggregation; 4-deep pipelined gathers =================
// MODE 1: value = T[d].xyz * T[d].w (u4, .w = nrm[d]); store z = nrm^2 * acc
// MODE 2: value = T[d].xyz (z4 pre-scaled);            store p = nrm * acc

template<int MODE>
__global__ __launch_bounds__(1024) void k_agg(const unsigned int* __restrict__ pk,
                                              const int* __restrict__ gcur,
                                              const float4* __restrict__ T, const float* __restrict__ nrm,
                                              float4* __restrict__ outv) {
    __shared__ float s0[RR], s1[RR], s2[RR];
    int b = blockIdx.x;
    int t = threadIdx.x;
    int nlo = b * RR;
    int nn = NN - nlo; if (nn > RR) nn = RR;
    if (nn <= 0) return;
    if (t < RR) { s0[t] = 0.f; s1[t] = 0.f; s2[t] = 0.f; }
    __syncthreads();
    const unsigned int* P = pk + b * CAP;
    int m = gcur[b]; if (m > CAP) m = CAP;
    int i = t;
    for (; i + 3072 < m; i += 4096) {
        unsigned int w0 = P[i];
        unsigned int w1 = P[i + 1024];
        unsigned int w2 = P[i + 2048];
        unsigned int w3 = P[i + 3072];
        float4 v0 = T[w0 & 0x1FFFFu];
        float4 v1 = T[w1 & 0x1FFFFu];
        float4 v2 = T[w2 & 0x1FFFFu];
        float4 v3 = T[w3 & 0x1FFFFu];
        if (MODE == 1) {
            v0.x *= v0.w; v0.y *= v0.w; v0.z *= v0.w;
            v1.x *= v1.w; v1.y *= v1.w; v1.z *= v1.w;
            v2.x *= v2.w; v2.y *= v2.w; v2.z *= v2.w;
            v3.x *= v3.w; v3.y *= v3.w; v3.z *= v3.w;
        }
        int r0 = (int)(w0 >> 17), r1 = (int)(w1 >> 17), r2 = (int)(w2 >> 17), r3 = (int)(w3 >> 17);
        atomicAdd(&s0[r0], v0.x); atomicAdd(&s1[r0], v0.y); atomicAdd(&s2[r0], v0.z);
        atomicAdd(&s0[r1], v1.x); atomicAdd(&s1[r1], v1.y); atomicAdd(&s2[r1], v1.z);
        atomicAdd(&s0[r2], v2.x); atomicAdd(&s1[r2], v2.y); atomicAdd(&s2[r2], v2.z);
        atomicAdd(&s0[r3], v3.x); atomicAdd(&s1[r3], v3.y); atomicAdd(&s2[r3], v3.z);
    }
    for (; i < m; i += 1024) {
        unsigned int wa = P[i];
        float4 va = T[wa & 0x1FFFFu];
        float ax = va.x, ay = va.y, az = va.z;
        if (MODE == 1) { ax *= va.w; ay *= va.w; az *= va.w; }
        int ra = (int)(wa >> 17);
        atomicAdd(&s0[ra], ax); atomicAdd(&s1[ra], ay); atomicAdd(&s2[ra], az);
    }
    __syncthreads();
    for (int j = t; j < nn; j += 1024) {
        float nv = nrm[nlo + j];
        float sc = (MODE == 1) ? nv * nv : nv;
        outv[nlo + j] = make_float4(sc * s0[j], sc * s1[j], sc * s2[j], 0.f);
    }
}

// ================= D5: edge outputs: 4 edges/thread, int4 index loads, float4 stores =================

__global__ __launch_bounds__(512) void k_edge(const int* __restrict__ esrc, const int* __restrict__ edst,
                                              const int* __restrict__ sfake, const int* __restrict__ dfake,
                                              const float4* __restrict__ p4, float* __restrict__ out) {
    int t = threadIdx.x;
    int e0 = blockIdx.x * 2048 + t * 4;
    if (e0 >= EE) return;
    int4 s4  = *(const int4*)(esrc + e0);
    int4 d4  = *(const int4*)(edst + e0);
    int4 sf4 = *(const int4*)(sfake + e0);
    int4 df4 = *(const int4*)(dfake + e0);
    int ss[4] = { s4.x, s4.y, s4.z, s4.w };
    int dd[4] = { d4.x, d4.y, d4.z, d4.w };
    int sf[4] = { sf4.x, sf4.y, sf4.z, sf4.w };
    int df[4] = { df4.x, df4.y, df4.z, df4.w };
    float o0[4], o1[4], o2[4], o3[4], o4[4], o5[4];
    #pragma unroll
    for (int j = 0; j < 4; ++j) {
        int sfj = sf[j]; sfj = sfj < 0 ? 0 : (sfj >= NN ? NN - 1 : sfj);
        int dfj = df[j]; dfj = dfj < 0 ? 0 : (dfj >= NN ? NN - 1 : dfj);
        float4 ps = p4[ss[j]], pd = p4[dd[j]], psf = p4[sfj], pdf = p4[dfj];
        o0[j] = expf(ps.x + pd.x);
        o1[j] = expf(ps.y + pd.y);
        o2[j] = 1.f / (1.f + expf(-(ps.z * pd.z)));
        o3[j] = expf(psf.x + 128.f * pdf.y);
        o4[j] = expf(psf.y + pdf.y);
        o5[j] = 1.f / (1.f + expf(-(ps.z * pdf.z)));
    }
    *(float4*)(out + e0)                  = make_float4(o0[0], o0[1], o0[2], o0[3]);
    *(float4*)(out + (size_t)EE + e0)     = make_float4(o1[0], o1[1], o1[2], o1[3]);
    *(float4*)(out + (size_t)2 * EE + e0) = make_float4(o2[0], o2[1], o2[2], o2[3]);
    *(float4*)(out + (size_t)3 * EE + e0) = make_float4(o3[0], o3[1], o3[2], o3[3]);
    *(float4*)(out + (size_t)4 * EE + e0) = make_float4(o4[0], o4[1], o4[2], o4[3]);
    *(float4*)(out + (size_t)5 * EE + e0) = make_float4(o5[0], o5[1], o5[2], o5[3]);
}

// ---------------- launch ----------------

extern "C" void kernel_launch(void* const* d_in, const int* in_sizes, int n_in,
                              void* d_out, int out_size, void* d_ws, size_t ws_size,
                              hipStream_t stream) {
    const float* h       = (const float*)d_in[0];
    const float* w_gcn0  = (const float*)d_in[1];
    const float* w_gcn1  = (const float*)d_in[2];
    const float* w_rate0 = (const float*)d_in[3];
    const float* w_rate1 = (const float*)d_in[4];
    const float* w_alpha = (const float*)d_in[5];
    const int* edge_src  = (const int*)d_in[6];
    const int* edge_dst  = (const int*)d_in[7];
    const int* src_fake  = (const int*)d_in[8];
    const int* dst_fake  = (const int*)d_in[9];
    float* out = (float*)d_out;

    char* p = (char*)d_ws;
    auto alloc = [&](size_t bytes) {
        char* r = p;
        p += (bytes + 255) & ~(size_t)255;
        return r;
    };
    unsigned int* pk = (unsigned int*)alloc((size_t)KB * CAP * 4);   // 8.4 MB
    int* gcur   = (int*)alloc(KB * 4);
    float* nrm  = (float*)alloc((size_t)NN * 4);
    float4* u4  = (float4*)alloc((size_t)NN * 16);
    float4* z4  = (float4*)alloc((size_t)NN * 16);
    float4* p4  = (float4*)alloc((size_t)NN * 16);
    float* Pt0  = (float*)alloc(512);
    float* Pt1  = (float*)alloc(512);
    float* Pt2  = (float*)alloc(512);

    k_pmat<<<1, 1024, 0, stream>>>(w_gcn0, w_gcn1, w_rate0, w_rate1, w_alpha,
                                   Pt0, Pt1, Pt2, gcur);
    k_part_proj<<<NPART + NPROJ, 512, 0, stream>>>(edge_src, edge_dst, gcur, pk, h,
                                                   Pt0, Pt1, Pt2, u4);
    k_cnt<<<KB, 1024, 0, stream>>>(pk, gcur, nrm, u4);
    k_agg<1><<<KB, 1024, 0, stream>>>(pk, gcur, u4, nrm, z4);
    k_agg<2><<<KB, 1024, 0, stream>>>(pk, gcur, z4, nrm, p4);
    k_edge<<<(EE + 2047) / 2048, 512, 0, stream>>>(edge_src, edge_dst, src_fake, dst_fake, p4, out);
}

// Round 14
// 223.141 us; speedup vs baseline: 1.0421x; 1.0421x over previous
//
#include <hip/hip_runtime.h>
#include <math.h>

#define NN 100000
#define EE 1600000
#define KB 256          // buckets
#define RR 391          // ceil(NN / KB); srel < 391, dst < 2^17
#define CAP 8192        // per-bucket capacity (avg 6250, sigma ~76)
#define PARTB 782       // part blocks: 2048 edges each
#define PROJB 391       // proj blocks: 256 nodes each

// ---------------- P = W0 @ W1 @ [rowsum(w_rate0) | w_rate1 | w_alpha]  (128x3); also zero gcur ----------------

__global__ __launch_bounds__(1024) void k_pmat(const float* __restrict__ w_gcn0,
                                               const float* __restrict__ w_gcn1,
                                               const float* __restrict__ w_rate0,
                                               const float* __restrict__ w_rate1,
                                               const float* __restrict__ w_alpha,
                                               float* __restrict__ Pt0, float* __restrict__ Pt1,
                                               float* __restrict__ Pt2, int* __restrict__ gcur) {
    __shared__ float V0[128], V1[128], V2[128];
    __shared__ float Q0[128], Q1[128], Q2[128];
    int t = threadIdx.x;
    if (t < KB) gcur[t] = 0;
    int r = t >> 3, seg = t & 7;
    {   // V0 = rowsum(w_rate0)
        const float* p = w_rate0 + r * 128 + seg * 16;
        float s = 0.f;
        #pragma unroll
        for (int k = 0; k < 16; ++k) s += p[k];
        s += __shfl_down(s, 4, 8); s += __shfl_down(s, 2, 8); s += __shfl_down(s, 1, 8);
        if (seg == 0) V0[r] = s;
    }
    if (t < 128) { V1[t] = w_rate1[t]; V2[t] = w_alpha[t]; }
    __syncthreads();
    {   // Q = w_gcn1 @ V
        const float* p = w_gcn1 + r * 128 + seg * 16;
        float q0 = 0.f, q1 = 0.f, q2 = 0.f;
        #pragma unroll
        for (int k = 0; k < 16; ++k) {
            float w = p[k]; int j = seg * 16 + k;
            q0 += w * V0[j]; q1 += w * V1[j]; q2 += w * V2[j];
        }
        q0 += __shfl_down(q0, 4, 8); q0 += __shfl_down(q0, 2, 8); q0 += __shfl_down(q0, 1, 8);
        q1 += __shfl_down(q1, 4, 8); q1 += __shfl_down(q1, 2, 8); q1 += __shfl_down(q1, 1, 8);
        q2 += __shfl_down(q2, 4, 8); q2 += __shfl_down(q2, 2, 8); q2 += __shfl_down(q2, 1, 8);
        if (seg == 0) { Q0[r] = q0; Q1[r] = q1; Q2[r] = q2; }
    }
    __syncthreads();
    {   // P = w_gcn0 @ Q
        const float* p = w_gcn0 + r * 128 + seg * 16;
        float q0 = 0.f, q1 = 0.f, q2 = 0.f;
        #pragma unroll
        for (int k = 0; k < 16; ++k) {
            float w = p[k]; int j = seg * 16 + k;
            q0 += w * Q0[j]; q1 += w * Q1[j]; q2 += w * Q2[j];
        }
        q0 += __shfl_down(q0, 4, 8); q0 += __shfl_down(q0, 2, 8); q0 += __shfl_down(q0, 1, 8);
        q1 += __shfl_down(q1, 4, 8); q1 += __shfl_down(q1, 2, 8); q1 += __shfl_down(q1, 1, 8);
        q2 += __shfl_down(q2, 4, 8); q2 += __shfl_down(q2, 2, 8); q2 += __shfl_down(q2, 1, 8);
        if (seg == 0) { Pt0[r] = q0; Pt1[r] = q1; Pt2[r] = q2; }
    }
}

// ---------------- fused: part (even role) + raw projection u = h@P (odd role) ----------------
// 782 blocks x 512 threads. role = blockIdx&1, id = blockIdx>>1 (0..390).
// part: edges [id*4096, +4096), 8/thread. proj: nodes [id*256, +256), stores u4.xyz ONLY (.w set later by k_cnt).

__global__ __launch_bounds__(512) void k_part_proj(const int* __restrict__ src, const int* __restrict__ dst,
                                                   int* __restrict__ gcur, unsigned int* __restrict__ pk,
                                                   const float* __restrict__ h,
                                                   const float* __restrict__ Pt0, const float* __restrict__ Pt1,
                                                   const float* __restrict__ Pt2,
                                                   float4* __restrict__ u4) {
    __shared__ int cnt[KB];
    __shared__ int base[KB];
    __shared__ float sP0[128], sP1[128], sP2[128];
    int t = threadIdx.x;
    int role = blockIdx.x & 1;
    int id = blockIdx.x >> 1;

    if (role == 0) {
        // ---- partition ----
        if (t < KB) cnt[t] = 0;
        __syncthreads();
        int e0 = id * 4096;
        unsigned int pkv[8];
        int bkt[8];
        #pragma unroll
        for (int i = 0; i < 8; ++i) {
            int e = e0 + i * 512 + t;
            if (e < EE) {
                int s = src[e];
                int d = dst[e];
                int b = s / RR;
                bkt[i] = b;
                pkv[i] = (unsigned int)d | ((unsigned int)(s - b * RR) << 17);
                atomicAdd(&cnt[b], 1);
            } else bkt[i] = -1;
        }
        __syncthreads();
        if (t < KB) base[t] = cnt[t] ? atomicAdd(&gcur[t], cnt[t]) : 0;
        __syncthreads();
        if (t < KB) cnt[t] = 0;
        __syncthreads();
        #pragma unroll
        for (int i = 0; i < 8; ++i) {
            if (bkt[i] >= 0) {
                int rr = atomicAdd(&cnt[bkt[i]], 1);
                int rel = base[bkt[i]] + rr;
                if (rel < CAP) pk[bkt[i] * CAP + rel] = pkv[i];   // overflow guard (stat. impossible)
            }
        }
    } else {
        // ---- raw projection (no nrm) ----
        if (t < 128) { sP0[t] = Pt0[t]; sP1[t] = Pt1[t]; sP2[t] = Pt2[t]; }
        __syncthreads();
        int hw = t >> 5;       // 0..15
        int l32 = t & 31;
        int c4 = l32 * 4;
        float4 c0 = *(const float4*)(sP0 + c4);
        float4 c1 = *(const float4*)(sP1 + c4);
        float4 c2 = *(const float4*)(sP2 + c4);
        int nlo = id * 256;
        for (int i0 = 0; i0 < 256; i0 += 16) {
            int node = nlo + i0 + hw;
            if (node < NN) {
                float4 hv = *(const float4*)(h + (size_t)node * 128 + c4);
                float p0v = hv.x * c0.x + hv.y * c0.y + hv.z * c0.z + hv.w * c0.w;
                float p1v = hv.x * c1.x + hv.y * c1.y + hv.z * c1.z + hv.w * c1.w;
                float p2v = hv.x * c2.x + hv.y * c2.y + hv.z * c2.z + hv.w * c2.w;
                #pragma unroll
                for (int off = 16; off > 0; off >>= 1) {
                    p0v += __shfl_down(p0v, off, 32);
                    p1v += __shfl_down(p1v, off, 32);
                    p2v += __shfl_down(p2v, off, 32);
                }
                if (l32 == 0) {
                    float* up = (float*)&u4[node];
                    *(float2*)up = make_float2(p0v, p1v);   // .xy
                    up[2] = p2v;                            // .z   (.w untouched)
                }
            }
        }
    }
}

// ---------------- cnt: degrees from pk -> nrm[]; stow nrm into u4.w ----------------

__global__ __launch_bounds__(1024) void k_cnt(const unsigned int* __restrict__ pk,
                                              const int* __restrict__ gcur,
                                              float* __restrict__ nrm, float4* __restrict__ u4) {
    __shared__ int c[RR];
    int b = blockIdx.x;
    int t = threadIdx.x;
    int nlo = b * RR;
    int nn = NN - nlo; if (nn > RR) nn = RR;
    if (nn <= 0) return;
    if (t < RR) c[t] = 0;
    __syncthreads();
    const unsigned int* P = pk + b * CAP;
    int m = gcur[b]; if (m > CAP) m = CAP;
    for (int i = t; i < m; i += 1024) atomicAdd(&c[P[i] >> 17], 1);
    __syncthreads();
    if (t < nn) {
        float nv = rsqrtf((float)c[t]);
        nrm[nlo + t] = nv;
        ((float*)&u4[nlo + t])[3] = nv;    // .w only
    }
}

// ---------------- bucketed aggregation; 2-deep pipelined gathers ----------------
// MODE 1: value = T[d].xyz * T[d].w (u4, .w = nrm[d]); store z = nrm^2 * acc
// MODE 2: value = T[d].xyz (z4 pre-scaled);            store p = nrm * acc

template<int MODE>
__global__ __launch_bounds__(1024) void k_agg(const unsigned int* __restrict__ pk,
                                              const int* __restrict__ gcur,
                                              const float4* __restrict__ T, const float* __restrict__ nrm,
                                              float4* __restrict__ outv) {
    __shared__ float s0[RR], s1[RR], s2[RR];
    int b = blockIdx.x;
    int t = threadIdx.x;
    int nlo = b * RR;
    int nn = NN - nlo; if (nn > RR) nn = RR;
    if (nn <= 0) return;
    if (t < RR) { s0[t] = 0.f; s1[t] = 0.f; s2[t] = 0.f; }
    __syncthreads();
    const unsigned int* P = pk + b * CAP;
    int m = gcur[b]; if (m > CAP) m = CAP;
    int i = t;
    for (; i + 1024 < m; i += 2048) {
        unsigned int wa = P[i];
        unsigned int wb = P[i + 1024];
        float4 va = T[wa & 0x1FFFFu];
        float4 vb = T[wb & 0x1FFFFu];
        float ax = va.x, ay = va.y, az = va.z;
        float bx = vb.x, by = vb.y, bz = vb.z;
        if (MODE == 1) { ax *= va.w; ay *= va.w; az *= va.w; bx *= vb.w; by *= vb.w; bz *= vb.w; }
        int ra = (int)(wa >> 17), rb = (int)(wb >> 17);
        atomicAdd(&s0[ra], ax); atomicAdd(&s1[ra], ay); atomicAdd(&s2[ra], az);
        atomicAdd(&s0[rb], bx); atomicAdd(&s1[rb], by); atomicAdd(&s2[rb], bz);
    }
    if (i < m) {
        unsigned int wa = P[i];
        float4 va = T[wa & 0x1FFFFu];
        float ax = va.x, ay = va.y, az = va.z;
        if (MODE == 1) { ax *= va.w; ay *= va.w; az *= va.w; }
        int ra = (int)(wa >> 17);
        atomicAdd(&s0[ra], ax); atomicAdd(&s1[ra], ay); atomicAdd(&s2[ra], az);
    }
    __syncthreads();
    for (int j = t; j < nn; j += 1024) {
        float nv = nrm[nlo + j];
        float sc = (MODE == 1) ? nv * nv : nv;
        outv[nlo + j] = make_float4(sc * s0[j], sc * s1[j], sc * s2[j], 0.f);
    }
}

// ---------------- edge outputs: 4 edges/thread, int4 index loads, float4 output stores ----------------

__global__ __launch_bounds__(256) void k_edge(const int* __restrict__ esrc, const int* __restrict__ edst,
                                              const int* __restrict__ sfake, const int* __restrict__ dfake,
                                              const float4* __restrict__ p4, float* __restrict__ out) {
    int t = threadIdx.x;
    int e0 = blockIdx.x * 1024 + t * 4;
    if (e0 >= EE) return;
    int4 s4  = *(const int4*)(esrc + e0);
    int4 d4  = *(const int4*)(edst + e0);
    int4 sf4 = *(const int4*)(sfake + e0);
    int4 df4 = *(const int4*)(dfake + e0);
    int ss[4] = { s4.x, s4.y, s4.z, s4.w };
    int dd[4] = { d4.x, d4.y, d4.z, d4.w };
    int sf[4] = { sf4.x, sf4.y, sf4.z, sf4.w };
    int df[4] = { df4.x, df4.y, df4.z, df4.w };
    float o0[4], o1[4], o2[4], o3[4], o4[4], o5[4];
    #pragma unroll
    for (int j = 0; j < 4; ++j) {
        int sfj = sf[j]; sfj = sfj < 0 ? 0 : (sfj >= NN ? NN - 1 : sfj);
        int dfj = df[j]; dfj = dfj < 0 ? 0 : (dfj >= NN ? NN - 1 : dfj);
        float4 ps = p4[ss[j]], pd = p4[dd[j]], psf = p4[sfj], pdf = p4[dfj];
        o0[j] = expf(ps.x + pd.x);
        o1[j] = expf(ps.y + pd.y);
        o2[j] = 1.f / (1.f + expf(-(ps.z * pd.z)));
        o3[j] = expf(psf.x + 128.f * pdf.y);
        o4[j] = expf(psf.y + pdf.y);
        o5[j] = 1.f / (1.f + expf(-(ps.z * pdf.z)));
    }
    *(float4*)(out + e0)                  = make_float4(o0[0], o0[1], o0[2], o0[3]);
    *(float4*)(out + (size_t)EE + e0)     = make_float4(o1[0], o1[1], o1[2], o1[3]);
    *(float4*)(out + (size_t)2 * EE + e0) = make_float4(o2[0], o2[1], o2[2], o2[3]);
    *(float4*)(out + (size_t)3 * EE + e0) = make_float4(o3[0], o3[1], o3[2], o3[3]);
    *(float4*)(out + (size_t)4 * EE + e0) = make_float4(o4[0], o4[1], o4[2], o4[3]);
    *(float4*)(out + (size_t)5 * EE + e0) = make_float4(o5[0], o5[1], o5[2], o5[3]);
}

// ---------------- launch ----------------

extern "C" void kernel_launch(void* const* d_in, const int* in_sizes, int n_in,
                              void* d_out, int out_size, void* d_ws, size_t ws_size,
                              hipStream_t stream) {
    const float* h       = (const float*)d_in[0];
    const float* w_gcn0  = (const float*)d_in[1];
    const float* w_gcn1  = (const float*)d_in[2];
    const float* w_rate0 = (const float*)d_in[3];
    const float* w_rate1 = (const float*)d_in[4];
    const float* w_alpha = (const float*)d_in[5];
    const int* edge_src  = (const int*)d_in[6];
    const int* edge_dst  = (const int*)d_in[7];
    const int* src_fake  = (const int*)d_in[8];
    const int* dst_fake  = (const int*)d_in[9];
    float* out = (float*)d_out;

    char* p = (char*)d_ws;
    auto alloc = [&](size_t bytes) {
        char* r = p;
        p += (bytes + 255) & ~(size_t)255;
        return r;
    };
    unsigned int* pk = (unsigned int*)alloc((size_t)KB * CAP * 4);   // 8.4 MB
    int* gcur   = (int*)alloc(KB * 4);
    float* nrm  = (float*)alloc((size_t)NN * 4);
    float4* u4  = (float4*)alloc((size_t)NN * 16);
    float4* z4  = (float4*)alloc((size_t)NN * 16);
    float4* p4  = (float4*)alloc((size_t)NN * 16);
    float* Pt0  = (float*)alloc(512);
    float* Pt1  = (float*)alloc(512);
    float* Pt2  = (float*)alloc(512);

    k_pmat<<<1, 1024, 0, stream>>>(w_gcn0, w_gcn1, w_rate0, w_rate1, w_alpha,
                                   Pt0, Pt1, Pt2, gcur);
    k_part_proj<<<PARTB, 512, 0, stream>>>(edge_src, edge_dst, gcur, pk, h,
                                           Pt0, Pt1, Pt2, u4);
    k_cnt<<<KB, 1024, 0, stream>>>(pk, gcur, nrm, u4);
    k_agg<1><<<KB, 1024, 0, stream>>>(pk, gcur, u4, nrm, z4);
    k_agg<2><<<KB, 1024, 0, stream>>>(pk, gcur, z4, nrm, p4);
    k_edge<<<(EE + 1023) / 1024, 256, 0, stream>>>(edge_src, edge_dst, src_fake, dst_fake, p4, out);
}